// Round 2
// baseline (2294.011 us; speedup 1.0000x reference)
//
#include <hip/hip_runtime.h>
#include <hip/hip_bf16.h>
#include <math.h>

#define B_ 128
#define T_ 128
#define D_ 512
#define STEPS_ 255
#define NCOMP_ 128

#define REF_COMP 4096
#define REF_ZERO 8192

using short8  = __attribute__((ext_vector_type(8))) short;
using ushort8 = __attribute__((ext_vector_type(8))) unsigned short;
using float4v = __attribute__((ext_vector_type(4))) float;

__device__ __forceinline__ unsigned short rne_bf16(float f){
  union { float f; unsigned u; } v; v.f = f;
  unsigned u = v.u;
  u += 0x7FFFu + ((u >> 16) & 1u);
  return (unsigned short)(u >> 16);
}

// parity grouping: LDS-group j -> batch row (evens first, then odds)
__device__ __forceinline__ int rowB(int j){ return (j < 64) ? (2*j) : (2*(j-64)+1); }

// ---------------- pre-pass: symbolic stack simulation ----------------
// ref encoding: 0..127 = BUF idx; 4096+k = COMP k; 8192 = initial zero slot; -1 = no reduce
__global__ void k_prepass(const int* __restrict__ tr, int* __restrict__ redK,
                          int* __restrict__ redL, int* __restrict__ redR,
                          int* __restrict__ encRef){
  int b = threadIdx.x;
  if (b >= B_) return;
  short stk[T_ + 2];
  stk[0] = (short)REF_ZERO; stk[1] = (short)REF_ZERO;
  int ptr = 2, bptr = 0, k = 0;
  for (int t = 0; t < STEPS_; t++){
    int tt = tr[b*STEPS_ + t];
    int rl = -1, rr = -1, rk = -1;
    if (tt == 0){                      // SHIFT: write BUF(bptr) at ptr
      int j = bptr; if (j > T_-1) j = T_-1;
      int wi = ptr; if (wi < 0) wi = 0; if (wi > T_+1) wi = T_+1;
      stk[wi] = (short)j;
      ptr++; bptr++;
    } else if (tt == 1){               // REDUCE
      int i1 = ptr-1; if (i1 < 0) i1 = 0; if (i1 > T_+1) i1 = T_+1;
      int i2 = ptr-2; if (i2 < 0) i2 = 0; if (i2 > T_+1) i2 = T_+1;
      rr = stk[i1]; rl = stk[i2]; rk = k;
      int wi = ptr-2; if (wi < 0) wi = 0; if (wi > T_+1) wi = T_+1;
      stk[wi] = (short)(REF_COMP + k);
      k++; ptr--;
    }                                   // SKIP: identity write, no ref change
    redK[b*STEPS_ + t] = rk;
    redL[b*STEPS_ + t] = rl;
    redR[b*STEPS_ + t] = rr;
  }
  int ei = ptr-1; if (ei < 0) ei = 0; if (ei > T_+1) ei = T_+1;
  encRef[b] = stk[ei];
}

// ---------------- W prep: fp32 [1024][512] -> bf16 MFMA-B-fragment-linear ----
// Wo[(((nt*32 + kt)*64) + lane)*8 + e] = bf16( W[kt*32 + (lane>>4)*8 + e][nt*16 + (lane&15)] )
__global__ void k_wprep(const float* __restrict__ W, unsigned short* __restrict__ Wo){
  int t = blockIdx.x*256 + threadIdx.x;           // t < 32*32*64*8 = 524288
  int e  = t & 7;
  int l  = (t >> 3) & 63;
  int kt = (t >> 9) & 31;
  int nt = (t >> 14);
  int krow = kt*32 + (l >> 4)*8 + e;
  int ncol = nt*16 + (l & 15);
  Wo[t] = rne_bf16(W[krow*512 + ncol]);
}

// ---------------- staging helper: 16 fp32 -> bf16 into swizzled LDS A row ----
__device__ __forceinline__ void stage16(char* Ab, int i, int col, const float* src16){
  ushort8 lo, hi;
  if (src16){
    #pragma unroll
    for (int e = 0; e < 8; e += 4){
      float4v f = *reinterpret_cast<const float4v*>(src16 + e);
      lo[e] = rne_bf16(f[0]); lo[e+1] = rne_bf16(f[1]);
      lo[e+2] = rne_bf16(f[2]); lo[e+3] = rne_bf16(f[3]);
    }
    #pragma unroll
    for (int e = 0; e < 8; e += 4){
      float4v f = *reinterpret_cast<const float4v*>(src16 + 8 + e);
      hi[e] = rne_bf16(f[0]); hi[e+1] = rne_bf16(f[1]);
      hi[e+2] = rne_bf16(f[2]); hi[e+3] = rne_bf16(f[3]);
    }
  } else {
    lo = (ushort8)0; hi = (ushort8)0;
  }
  int base = i*2048 + col*2;                      // row stride 2048 B (1024 bf16)
  int sw = (i & 7) << 4;                          // XOR swizzle (G4 fix)
  *reinterpret_cast<ushort8*>(Ab + ((base     ) ^ sw)) = lo;
  *reinterpret_cast<ushort8*>(Ab + ((base + 16) ^ sw)) = hi;
}

// ---------------- chain: per-WG 16 rows, lockstep over 255 steps ------------
__global__ __launch_bounds__(512) void k_chain(
    const float* __restrict__ bufs, const float* __restrict__ bias,
    const unsigned short* __restrict__ Wo,
    const int* __restrict__ redK, const int* __restrict__ redL,
    const int* __restrict__ redR, float* __restrict__ C)
{
  __shared__ unsigned short Ash[16*1024];         // A = [left;right] bf16, 32 KiB
  __shared__ int kArr[16], lArr[16], rArr[16], latest[16];
  const int tid = threadIdx.x, lane = tid & 63, w = tid >> 6, wg = blockIdx.x;
  char* Ab = (char*)Ash;

  for (int x = tid; x < 16*1024; x += 512) Ash[x] = 0;
  if (tid < 16) latest[tid] = -1;
  __syncthreads();

  float bs[4];
  #pragma unroll
  for (int j = 0; j < 4; j++) bs[j] = bias[(w*4 + j)*16 + (lane & 15)];

  const int m_ = lane & 15, kg = lane >> 4;
  const int abase = m_*2048 + kg*16;
  const int asw = (m_ & 7) << 4;

  for (int t = 0; t < STEPS_; t++){
    if (tid < 16){
      int b = rowB(wg*16 + tid);
      kArr[tid] = redK[b*STEPS_ + t];
      lArr[tid] = redL[b*STEPS_ + t];
      rArr[tid] = redR[b*STEPS_ + t];
    }
    __syncthreads();
    int anyv = 0;
    #pragma unroll
    for (int i2 = 0; i2 < 16; i2++) anyv |= (kArr[i2] >= 0) ? 1 : 0;
    if (!anyv){ __syncthreads(); continue; }      // uniform branch (LDS data)

    // ---- stage A operands (right always; left only if not the resident c) ----
    {
      const int i = tid >> 5, sub = tid & 31, c0 = sub*16;
      if (kArr[i] >= 0){
        int b = rowB(wg*16 + i);
        int rr = rArr[i];
        const float* srcR = nullptr;
        if (rr >= 0 && rr < REF_COMP)
          srcR = bufs + ((size_t)b*T_ + rr)*D_ + c0;
        else if (rr >= REF_COMP && rr < REF_ZERO)
          srcR = C + ((size_t)b*NCOMP_ + (rr - REF_COMP))*D_ + c0;
        stage16(Ab, i, 512 + c0, srcR);
        int rl = lArr[i];
        bool skipL = (rl >= REF_COMP && rl < REF_ZERO && (rl - REF_COMP) == latest[i]);
        if (!skipL){
          const float* srcL = nullptr;
          if (rl >= 0 && rl < REF_COMP)
            srcL = bufs + ((size_t)b*T_ + rl)*D_ + c0;
          else if (rl >= REF_COMP && rl < REF_ZERO)
            srcL = C + ((size_t)b*NCOMP_ + (rl - REF_COMP))*D_ + c0;
          stage16(Ab, i, c0, srcL);
        }
      }
    }
    __syncthreads();

    // ---- MFMA: M=16 rows, N=512 (wave owns 4 N-tiles), K=1024 (32 k-tiles) ----
    float4v acc[4];
    #pragma unroll
    for (int j = 0; j < 4; j++) acc[j] = (float4v){0.f, 0.f, 0.f, 0.f};
    #pragma unroll 8
    for (int kt = 0; kt < 32; kt++){
      short8 a = *reinterpret_cast<const short8*>(Ab + ((abase + kt*64) ^ asw));
      #pragma unroll
      for (int j = 0; j < 4; j++){
        const short8* bp = reinterpret_cast<const short8*>(Wo)
                           + (((w*4 + j)*32 + kt)*64 + lane);
        acc[j] = __builtin_amdgcn_mfma_f32_16x16x32_bf16(a, *bp, acc[j], 0, 0, 0);
      }
    }
    __syncthreads();                              // A fully consumed

    // ---- tanh + writeback (C fp32 global, bf16 into A-left as the new c) ----
    #pragma unroll
    for (int j = 0; j < 4; j++){
      int n = (w*4 + j)*16 + (lane & 15);
      #pragma unroll
      for (int r = 0; r < 4; r++){
        int m = (lane >> 4)*4 + r;               // D row = (lane>>4)*4 + reg
        int k = kArr[m];
        if (k >= 0){
          float v = tanhf(acc[j][r] + bs[j]);
          int b = rowB(wg*16 + m);
          C[((size_t)b*NCOMP_ + k)*D_ + n] = v;
          int base = m*2048 + n*2;
          *reinterpret_cast<unsigned short*>(Ab + (base ^ ((m & 7) << 4))) = rne_bf16(v);
        }
      }
    }
    __syncthreads();
    if (tid < 16 && kArr[tid] >= 0) latest[tid] = kArr[tid];
  }
}

// ---------------- output writer: pure copy/scatter, memory-bound ------------
__global__ __launch_bounds__(256) void k_out(
    const float* __restrict__ bufs, const float* __restrict__ C,
    const int* __restrict__ redL, const int* __restrict__ redR,
    const int* __restrict__ encRef, float* __restrict__ out)
{
  int r = blockIdx.x*2 + (threadIdx.x >> 7);      // 65536 output rows of 512 f32
  int q = threadIdx.x & 127;                      // float4 index within row
  int ref, b;
  float* dst;
  if (r < B_){                                    // enc block
    b = r; ref = encRef[r];
    dst = out + (size_t)r*D_;
  } else {                                        // attended block
    int z = r - B_;
    b = z / 511; int s = z - b*511;
    dst = out + (size_t)B_*D_ + (size_t)z*D_;
    if (s == 510) ref = encRef[b];
    else { int t = s >> 1; ref = (s & 1) ? redR[b*STEPS_ + t] : redL[b*STEPS_ + t]; }
  }
  float4v v = {0.f, 0.f, 0.f, 0.f};
  if (ref >= 0 && ref < REF_ZERO){
    const float* src = (ref < REF_COMP)
        ? (bufs + ((size_t)b*T_ + ref)*D_)
        : (C + ((size_t)b*NCOMP_ + (ref - REF_COMP))*D_);
    v = reinterpret_cast<const float4v*>(src)[q];
  }
  reinterpret_cast<float4v*>(dst)[q] = v;
}

// ---------------- launch ----------------------------------------------------
extern "C" void kernel_launch(void* const* d_in, const int* in_sizes, int n_in,
                              void* d_out, int out_size, void* d_ws, size_t ws_size,
                              hipStream_t stream){
  const float* bufs = (const float*)d_in[0];
  const float* W    = (const float*)d_in[1];
  const float* bias = (const float*)d_in[2];
  const int*   tr   = (const int*)d_in[3];
  float* out = (float*)d_out;
  char* ws = (char*)d_ws;

  float* C            = (float*)(ws);                         // 33,554,432 B
  unsigned short* Wo  = (unsigned short*)(ws + 33554432);     //  1,048,576 B
  int* redK           = (int*)(ws + 34603008);                //    130,560 B
  int* redL           = (int*)(ws + 34733568);                //    130,560 B
  int* redR           = (int*)(ws + 34864128);                //    130,560 B
  int* encRef         = (int*)(ws + 34994688);                //        512 B

  k_prepass<<<1, 128, 0, stream>>>(tr, redK, redL, redR, encRef);
  k_wprep<<<2048, 256, 0, stream>>>(W, Wo);
  k_chain<<<8, 512, 0, stream>>>(bufs, bias, Wo, redK, redL, redR, C);
  k_out<<<32768, 256, 0, stream>>>(bufs, C, redL, redR, encRef, out);
}

// Round 4
// 1198.453 us; speedup vs baseline: 1.9141x; 1.9141x over previous
//
#include <hip/hip_runtime.h>
#include <hip/hip_bf16.h>
#include <math.h>

#define B_ 128
#define T_ 128
#define D_ 512
#define STEPS_ 255

#define REF_COMP 4096
#define REF_ZERO 8192

using short8   = __attribute__((ext_vector_type(8))) short;
using ushort8  = __attribute__((ext_vector_type(8))) unsigned short;
using ushort4v = __attribute__((ext_vector_type(4))) unsigned short;
using float4v  = __attribute__((ext_vector_type(4))) float;

__device__ __forceinline__ unsigned short rne_bf16(float f){
  union { float f; unsigned u; } v; v.f = f;
  unsigned u = v.u;
  u += 0x7FFFu + ((u >> 16) & 1u);
  return (unsigned short)(u >> 16);
}
__device__ __forceinline__ float bf2f(unsigned short u){
  union { unsigned u; float f; } x; x.u = ((unsigned)u) << 16; return x.f;
}
// parity grouping: group-slot j -> batch row (evens first, then odds)
__device__ __forceinline__ int rowB(int j){ return (j < 64) ? (2*j) : (2*(j-64)+1); }

// ---------------- pre-pass: symbolic stack simulation ------------------------
// ref encoding: 0..127 = BUF idx; 4096+k = COMP k; 8192 = initial zero; -1 = none
__global__ void k_prepass(const int* __restrict__ tr,
                          int* __restrict__ redL, int* __restrict__ redR,
                          int* __restrict__ redL2, int* __restrict__ redR2,
                          int* __restrict__ nred, int* __restrict__ gIter,
                          int* __restrict__ encRef){
  __shared__ short nsh[B_];
  int b = threadIdx.x;
  if (b < B_){
    short stk[T_ + 2];
    stk[0] = (short)REF_ZERO; stk[1] = (short)REF_ZERO;
    int ptr = 2, bptr = 0, k = 0;
    for (int t = 0; t < STEPS_; t++){
      int tt = tr[b*STEPS_ + t];
      int rl = -1, rr = -1;
      if (tt == 0){                      // SHIFT
        int j = bptr; if (j > T_-1) j = T_-1;
        int wi = ptr; if (wi < 0) wi = 0; if (wi > T_+1) wi = T_+1;
        stk[wi] = (short)j;
        ptr++; bptr++;
      } else if (tt == 1){               // REDUCE
        int i1 = ptr-1; if (i1 < 0) i1 = 0; if (i1 > T_+1) i1 = T_+1;
        int i2 = ptr-2; if (i2 < 0) i2 = 0; if (i2 > T_+1) i2 = T_+1;
        rr = stk[i1]; rl = stk[i2];
        redL2[b*128 + k] = rl; redR2[b*128 + k] = rr;
        int wi = ptr-2; if (wi < 0) wi = 0; if (wi > T_+1) wi = T_+1;
        stk[wi] = (short)(REF_COMP + k);
        k++; ptr--;
      }                                  // SKIP: no change
      redL[b*STEPS_ + t] = rl;
      redR[b*STEPS_ + t] = rr;
    }
    int ei = ptr-1; if (ei < 0) ei = 0; if (ei > T_+1) ei = T_+1;
    encRef[b] = stk[ei];
    nred[b] = k; nsh[b] = (short)k;
  }
  __syncthreads();
  if (b < 8){
    int mx = 0;
    for (int i = 0; i < 16; i++){ int rb = rowB(b*16 + i); int v = nsh[rb]; if (v > mx) mx = v; }
    gIter[b] = mx;
  }
}

// ---------------- W prep: fp32 [1024][512] -> bf16 MFMA-B-fragment-linear ----
// Wo[(((nt*32 + kt)*64) + lane)*8 + e] = bf16( W[kt*32 + (lane>>4)*8 + e][nt*16 + (lane&15)] )
__global__ void k_wprep(const float* __restrict__ W, unsigned short* __restrict__ Wo){
  int t = blockIdx.x*256 + threadIdx.x;           // t < 524288
  int e  = t & 7;
  int l  = (t >> 3) & 63;
  int kt = (t >> 9) & 31;
  int nt = (t >> 14);
  int krow = kt*32 + (l >> 4)*8 + e;
  int ncol = nt*16 + (l & 15);
  Wo[t] = rne_bf16(W[krow*512 + ncol]);
}

// ---------------- buf prep: bufs fp32 -> bf16; zero page; barrier counters ---
__global__ void k_bufprep(const float* __restrict__ bufs, unsigned short* __restrict__ BufBf,
                          unsigned short* __restrict__ zeroPg, int* __restrict__ done){
  size_t i = ((size_t)blockIdx.x*256 + threadIdx.x)*8;
  if (i < (size_t)B_*T_*D_){
    float4v f0 = *reinterpret_cast<const float4v*>(bufs + i);
    float4v f1 = *reinterpret_cast<const float4v*>(bufs + i + 4);
    ushort8 o;
    o[0]=rne_bf16(f0[0]); o[1]=rne_bf16(f0[1]); o[2]=rne_bf16(f0[2]); o[3]=rne_bf16(f0[3]);
    o[4]=rne_bf16(f1[0]); o[5]=rne_bf16(f1[1]); o[6]=rne_bf16(f1[2]); o[7]=rne_bf16(f1[3]);
    *reinterpret_cast<ushort8*>(BufBf + i) = o;
  }
  if (blockIdx.x == 0){
    if (threadIdx.x < 128) reinterpret_cast<ushort8*>(zeroPg)[threadIdx.x] = (ushort8)0;
    if (threadIdx.x >= 128 && threadIdx.x < 136) done[threadIdx.x - 128] = 0;
  }
}

// ---------------- chain: 8 groups x 16 WGs (N-slice 32), 1 wave/WG ----------
// Per iteration k: every row's k-th reduce. Cross-WG exchange of composed
// vectors through CompBf (global, indexed by k -> no WAR), per-group
// monotonic-counter barrier with agent-scope fences.
__global__ __launch_bounds__(64, 1) void k_chain2(
    const unsigned short* __restrict__ BufBf,
    const float* __restrict__ bias,
    const unsigned short* __restrict__ Wo,
    const int* __restrict__ redL2, const int* __restrict__ redR2,
    const int* __restrict__ nred, const int* __restrict__ gIter,
    const unsigned short* __restrict__ zeroPg,
    unsigned short* __restrict__ CompBf,
    int* __restrict__ done)
{
  __shared__ unsigned short Bsh[32768];           // 64 KiB W-slice (2 n-tiles, K=1024)
  const int lane = threadIdx.x;
  const int g = blockIdx.x >> 4, wgN = blockIdx.x & 15;

  // load W slice into LDS (fragment-linear, conflict-free b128 reads later)
  {
    const ushort8* src = reinterpret_cast<const ushort8*>(Wo) + (size_t)wgN*4096;
    ushort8* dst = reinterpret_cast<ushort8*>(Bsh);
    #pragma unroll 4
    for (int x = lane; x < 4096; x += 64) dst[x] = src[x];
  }
  // n-tile 0 B-fragments resident in VGPRs (halves LDS reads in the hot loop)
  short8 Breg[32];
  #pragma unroll
  for (int kt = 0; kt < 32; ++kt)
    Breg[kt] = *reinterpret_cast<const short8*>((const char*)Bsh + (size_t)(kt*64 + lane)*16);

  const int mIn  = lane & 15;                     // A-row this lane feeds (MFMA A layout)
  const int koff = (lane >> 4) * 16;              // byte offset inside 64B k-segment
  const int myb  = rowB(g*16 + mIn);
  const int myNred = nred[myb];
  const int iters  = gIter[g];
  int bS[4], nredS[4];                            // rows this lane's C-fragment covers
  #pragma unroll
  for (int j = 0; j < 4; ++j){
    int mrow = (lane >> 4)*4 + j;
    bS[j] = rowB(g*16 + mrow);
    nredS[j] = nred[bS[j]];
  }
  const int colLane = lane & 15;
  const float bc0 = bias[wgN*32 + colLane];
  const float bc1 = bias[wgN*32 + 16 + colLane];

  for (int k = 0; k < iters; ++k){
    bool valid = (k < myNred);
    int rl = valid ? redL2[myb*128 + k] : REF_ZERO;
    int rr = valid ? redR2[myb*128 + k] : REF_ZERO;
    const char* pL;
    if (rl < REF_COMP)      pL = (const char*)(BufBf + ((size_t)myb*T_ + rl)*D_);
    else if (rl < REF_ZERO) pL = (const char*)(CompBf + ((size_t)myb*128 + (rl - REF_COMP))*D_);
    else                    pL = (const char*)zeroPg;
    bool rComp = (rr >= REF_COMP) && (rr < REF_ZERO);
    const char* pR;
    if (rr >= 0 && rr < REF_COMP) pR = (const char*)(BufBf + ((size_t)myb*T_ + rr)*D_);
    else if (rComp)               pR = (const char*)(CompBf + ((size_t)myb*128 + (rr - REF_COMP))*D_);
    else                          pR = (const char*)zeroPg;

    // prefetch right operand when it doesn't depend on the barrier (buf/zero)
    short8 aR[16];
    if (!rComp){
      #pragma unroll
      for (int kt = 0; kt < 16; ++kt)
        aR[kt] = *reinterpret_cast<const short8*>(pR + kt*64 + koff);
    }

    if (k > 0){
      if (lane == 0){
        int guard = 0;
        while (__hip_atomic_load(done + g, __ATOMIC_RELAXED, __HIP_MEMORY_SCOPE_AGENT) < 16*k){
          __builtin_amdgcn_s_sleep(1);
          if (++guard > (1 << 27)) break;         // safety: never hang the GPU
        }
      }
      __builtin_amdgcn_fence(__ATOMIC_ACQUIRE, "agent");
    }

    if (rComp){
      #pragma unroll
      for (int kt = 0; kt < 16; ++kt)
        aR[kt] = *reinterpret_cast<const short8*>(pR + kt*64 + koff);
    }
    short8 aL[16];
    #pragma unroll
    for (int kt = 0; kt < 16; ++kt)
      aL[kt] = *reinterpret_cast<const short8*>(pL + kt*64 + koff);

    // 4 independent 16-deep MFMA chains (2 n-tiles x 2 K-halves)
    float4v c0a = {0.f,0.f,0.f,0.f}, c0b = {0.f,0.f,0.f,0.f};
    float4v c1a = {0.f,0.f,0.f,0.f}, c1b = {0.f,0.f,0.f,0.f};
    #pragma unroll
    for (int kt = 0; kt < 16; ++kt){
      short8 b1a = *reinterpret_cast<const short8*>((const char*)Bsh + (size_t)((32+kt)*64 + lane)*16);
      short8 b1b = *reinterpret_cast<const short8*>((const char*)Bsh + (size_t)((48+kt)*64 + lane)*16);
      c0a = __builtin_amdgcn_mfma_f32_16x16x32_bf16(aL[kt], Breg[kt],    c0a, 0, 0, 0);
      c1a = __builtin_amdgcn_mfma_f32_16x16x32_bf16(aL[kt], b1a,         c1a, 0, 0, 0);
      c0b = __builtin_amdgcn_mfma_f32_16x16x32_bf16(aR[kt], Breg[16+kt], c0b, 0, 0, 0);
      c1b = __builtin_amdgcn_mfma_f32_16x16x32_bf16(aR[kt], b1b,         c1b, 0, 0, 0);
    }
    float4v acc0 = c0a + c0b, acc1 = c1a + c1b;

    #pragma unroll
    for (int j = 0; j < 4; ++j){
      if (k < nredS[j]){
        float v0 = tanhf(acc0[j] + bc0);
        float v1 = tanhf(acc1[j] + bc1);
        size_t rb = ((size_t)bS[j]*128 + k)*D_;
        CompBf[rb + wgN*32 + colLane]      = rne_bf16(v0);
        CompBf[rb + wgN*32 + 16 + colLane] = rne_bf16(v1);
      }
    }
    __builtin_amdgcn_fence(__ATOMIC_RELEASE, "agent");
    if (lane == 0)
      __hip_atomic_fetch_add(done + g, 1, __ATOMIC_RELAXED, __HIP_MEMORY_SCOPE_AGENT);
  }
}

// ---------------- output writer: pure copy/scatter, memory-bound ------------
__global__ __launch_bounds__(256) void k_out(
    const float* __restrict__ bufs, const unsigned short* __restrict__ CompBf,
    const int* __restrict__ redL, const int* __restrict__ redR,
    const int* __restrict__ encRef, float* __restrict__ out)
{
  int r = blockIdx.x*2 + (threadIdx.x >> 7);      // 65536 output rows of 512 f32
  int q = threadIdx.x & 127;                      // float4 index within row
  int ref, b;
  float* dst;
  if (r < B_){                                    // enc block
    b = r; ref = encRef[r];
    dst = out + (size_t)r*D_;
  } else {                                        // attended block
    int z = r - B_;
    b = z / 511; int s = z - b*511;
    dst = out + (size_t)B_*D_ + (size_t)z*D_;
    if (s == 510) ref = encRef[b];
    else { int t = s >> 1; ref = (s & 1) ? redR[b*STEPS_ + t] : redL[b*STEPS_ + t]; }
  }
  float4v v = {0.f, 0.f, 0.f, 0.f};
  if (ref >= 0 && ref < REF_COMP){
    v = reinterpret_cast<const float4v*>(bufs + ((size_t)b*T_ + ref)*D_)[q];
  } else if (ref >= REF_COMP && ref < REF_ZERO){
    ushort4v u = reinterpret_cast<const ushort4v*>(CompBf + ((size_t)b*128 + (ref - REF_COMP))*D_)[q];
    v[0] = bf2f(u[0]); v[1] = bf2f(u[1]); v[2] = bf2f(u[2]); v[3] = bf2f(u[3]);
  }
  reinterpret_cast<float4v*>(dst)[q] = v;
}

// ---------------- launch ----------------------------------------------------
extern "C" void kernel_launch(void* const* d_in, const int* in_sizes, int n_in,
                              void* d_out, int out_size, void* d_ws, size_t ws_size,
                              hipStream_t stream){
  const float* bufs = (const float*)d_in[0];
  const float* W    = (const float*)d_in[1];
  const float* bias = (const float*)d_in[2];
  const int*   tr   = (const int*)d_in[3];
  float* out = (float*)d_out;
  char* ws = (char*)d_ws;

  unsigned short* Wo     = (unsigned short*)(ws);               //  1,048,576
  unsigned short* BufBf  = (unsigned short*)(ws + 1048576);     // 16,777,216
  unsigned short* CompBf = (unsigned short*)(ws + 17825792);    // 16,777,216
  int* redL   = (int*)(ws + 34603008);                          //    131,072
  int* redR   = (int*)(ws + 34734080);                          //    131,072
  int* redL2  = (int*)(ws + 34865152);                          //     65,536
  int* redR2  = (int*)(ws + 34930688);                          //     65,536
  int* nred   = (int*)(ws + 34996224);                          //        512
  int* encRef = (int*)(ws + 34996736);                          //        512
  int* gIter  = (int*)(ws + 34997248);                          //         64
  int* done   = (int*)(ws + 34997312);                          //         64
  unsigned short* zeroPg = (unsigned short*)(ws + 34997376);    //      2,048

  k_prepass<<<1, 128, 0, stream>>>(tr, redL, redR, redL2, redR2, nred, gIter, encRef);
  k_bufprep<<<4096, 256, 0, stream>>>(bufs, BufBf, zeroPg, done);
  k_wprep<<<2048, 256, 0, stream>>>(W, Wo);
  k_chain2<<<128, 64, 0, stream>>>(BufBf, bias, Wo, redL2, redR2, nred, gIter,
                                   zeroPg, CompBf, done);
  k_out<<<32768, 256, 0, stream>>>(bufs, CompBf, redL, redR, encRef, out);
}

// Round 5
// 922.067 us; speedup vs baseline: 2.4879x; 1.2997x over previous
//
#include <hip/hip_runtime.h>
#include <hip/hip_bf16.h>
#include <math.h>

#define B_ 128
#define T_ 128
#define D_ 512
#define STEPS_ 255

#define REF_COMP 4096
#define REF_ZERO 8192

using short8   = __attribute__((ext_vector_type(8))) short;
using ushort8  = __attribute__((ext_vector_type(8))) unsigned short;
using ushort4v = __attribute__((ext_vector_type(4))) unsigned short;
using float4v  = __attribute__((ext_vector_type(4))) float;

__device__ __forceinline__ unsigned short rne_bf16(float f){
  union { float f; unsigned u; } v; v.f = f;
  unsigned u = v.u;
  u += 0x7FFFu + ((u >> 16) & 1u);
  return (unsigned short)(u >> 16);
}
__device__ __forceinline__ float bf2f(unsigned short u){
  union { unsigned u; float f; } x; x.u = ((unsigned)u) << 16; return x.f;
}
__device__ __forceinline__ float fast_tanh(float x){
  float xc = fminf(9.0f, fmaxf(-9.0f, x));
  float e  = __expf(2.0f * xc);
  return (e - 1.0f) * __builtin_amdgcn_rcpf(e + 1.0f);
}
// parity grouping: group-slot j -> batch row (evens first, then odds)
__device__ __forceinline__ int rowB(int j){ return (j < 64) ? (2*j) : (2*(j-64)+1); }

// ---------------- zero init: flags / bitmaps / zero page ---------------------
__global__ void k_zero(int* __restrict__ flags, int* __restrict__ anyLR,
                       int* __restrict__ gIter, unsigned short* __restrict__ zeroPg){
  int t = threadIdx.x;
  for (int i = t; i < 1024; i += 256) flags[i] = 0;
  for (int i = t; i < 1024; i += 256) anyLR[i] = 0;
  if (t < 16) gIter[t] = 0;
  for (int i = t; i < 1024; i += 256) zeroPg[i] = 0;
}

// ---------------- pre-pass: symbolic stack simulation (1 block / row) --------
// ref encoding: 0..127 = BUF idx; 4096+k = COMP k; 8192 = initial zero; -1 = none
__global__ __launch_bounds__(64) void k_prepass2(
    const int* __restrict__ tr,
    short* __restrict__ redL, short* __restrict__ redR,
    short* __restrict__ uL, short* __restrict__ uR,
    short* __restrict__ cL, short* __restrict__ cR,
    int* __restrict__ nred, int* __restrict__ encRef,
    int* __restrict__ gIter, int* __restrict__ anyLR){
  __shared__ int trs[STEPS_];
  int b = blockIdx.x, lane = threadIdx.x;
  for (int i = lane; i < STEPS_; i += 64) trs[i] = tr[b*STEPS_ + i];
  __syncthreads();
  if (lane != 0) return;
  short stk[T_ + 2];
  stk[0] = (short)REF_ZERO; stk[1] = (short)REF_ZERO;
  int ptr = 2, bptr = 0, k = 0;
  int g = (b & 1) ? 4 + ((b >> 1) >> 4) : ((b >> 1) >> 4);
  for (int t = 0; t < STEPS_; t++){
    int tt = trs[t];
    int rl = -1, rr = -1;
    if (tt == 0){                      // SHIFT
      int j = bptr; if (j > T_-1) j = T_-1;
      int wi = ptr; if (wi < 0) wi = 0; if (wi > T_+1) wi = T_+1;
      stk[wi] = (short)j;
      ptr++; bptr++;
    } else if (tt == 1){               // REDUCE
      int i1 = ptr-1; if (i1 < 0) i1 = 0; if (i1 > T_+1) i1 = T_+1;
      int i2 = ptr-2; if (i2 < 0) i2 = 0; if (i2 > T_+1) i2 = T_+1;
      rr = stk[i1]; rl = stk[i2];
      short sL = (rl >= 0 && rl < REF_COMP) ? (short)rl : (short)-1;   // static buf
      short sR = (rr >= 0 && rr < REF_COMP) ? (short)rr : (short)-1;
      short dL = (rl >= REF_COMP && rl < REF_ZERO) ? (short)(rl - REF_COMP) : (short)-1; // dyn comp
      short dR = (rr >= REF_COMP && rr < REF_ZERO) ? (short)(rr - REF_COMP) : (short)-1;
      uL[b*128 + k] = sL; uR[b*128 + k] = sR;
      cL[b*128 + k] = dL; cR[b*128 + k] = dR;
      int bits = (dL >= 0 ? 1 : 0) | (dR >= 0 ? 2 : 0);
      if (bits) atomicOr(anyLR + g*128 + k, bits);
      int wi = ptr-2; if (wi < 0) wi = 0; if (wi > T_+1) wi = T_+1;
      stk[wi] = (short)(REF_COMP + k);
      k++; ptr--;
    }                                  // SKIP: no change
    redL[b*STEPS_ + t] = (short)rl;
    redR[b*STEPS_ + t] = (short)rr;
  }
  for (int kk = k; kk < 128; kk++){
    uL[b*128+kk] = -1; uR[b*128+kk] = -1; cL[b*128+kk] = -1; cR[b*128+kk] = -1;
  }
  int ei = ptr-1; if (ei < 0) ei = 0; if (ei > T_+1) ei = T_+1;
  encRef[b] = stk[ei];
  nred[b] = k;
  atomicMax(gIter + g, k);
}

// ---------------- W prep: fp32 [1024][512] -> bf16 MFMA-B-fragment-linear ----
// Wo[(((nt*32 + kt)*64) + lane)*8 + e] = bf16( W[kt*32 + (lane>>4)*8 + e][nt*16 + (lane&15)] )
__global__ void k_wprep(const float* __restrict__ W, unsigned short* __restrict__ Wo){
  int t = blockIdx.x*256 + threadIdx.x;           // t < 524288
  int e  = t & 7;
  int l  = (t >> 3) & 63;
  int kt = (t >> 9) & 31;
  int nt = (t >> 14);
  int krow = kt*32 + (l >> 4)*8 + e;
  int ncol = nt*16 + (l & 15);
  Wo[t] = rne_bf16(W[krow*512 + ncol]);
}

// ---------------- U GEMM: U[(b,k)][col] = W_L*leftStatic + W_R*rightStatic + b
// M=16384 (b*128+k), N=512, K=1024. A gathered from bufs (fp32 -> bf16 on the fly).
__global__ __launch_bounds__(256) void k_ugemm(
    const float* __restrict__ bufs, const float* __restrict__ bias,
    const unsigned short* __restrict__ Wo,
    const short* __restrict__ uL, const short* __restrict__ uR,
    const float* __restrict__ zeroF, unsigned short* __restrict__ U){
  int mt = blockIdx.x & 255, ntB = blockIdx.x >> 8;
  int w = threadIdx.x >> 6, lane = threadIdx.x & 63;
  int rbase = mt*64 + w*16;
  int arow = rbase + (lane & 15);
  int b = arow >> 7;
  int refL = (int)uL[arow], refR = (int)uR[arow];
  const float* pL = (refL >= 0) ? (bufs + ((size_t)b*T_ + refL)*D_) : zeroF;
  const float* pR = (refR >= 0) ? (bufs + ((size_t)b*T_ + refR)*D_) : zeroF;
  int eoff = (lane >> 4) * 8;
  float4v acc[8];
  #pragma unroll
  for (int nt = 0; nt < 8; ++nt) acc[nt] = (float4v){0.f,0.f,0.f,0.f};
  for (int kt = 0; kt < 32; ++kt){
    const float* src = (kt < 16) ? pL : pR;
    int off = (kt & 15)*32 + eoff;
    float4v f0 = *reinterpret_cast<const float4v*>(src + off);
    float4v f1 = *reinterpret_cast<const float4v*>(src + off + 4);
    short8 a;
    a[0]=(short)rne_bf16(f0[0]); a[1]=(short)rne_bf16(f0[1]);
    a[2]=(short)rne_bf16(f0[2]); a[3]=(short)rne_bf16(f0[3]);
    a[4]=(short)rne_bf16(f1[0]); a[5]=(short)rne_bf16(f1[1]);
    a[6]=(short)rne_bf16(f1[2]); a[7]=(short)rne_bf16(f1[3]);
    #pragma unroll
    for (int nt = 0; nt < 8; ++nt){
      const short8* bp = reinterpret_cast<const short8*>(Wo)
                         + (((size_t)(ntB*8 + nt)*32 + kt)*64 + lane);
      acc[nt] = __builtin_amdgcn_mfma_f32_16x16x32_bf16(a, *bp, acc[nt], 0, 0, 0);
    }
  }
  #pragma unroll
  for (int nt = 0; nt < 8; ++nt){
    int col = ntB*128 + nt*16 + (lane & 15);
    float bc = bias[col];
    #pragma unroll
    for (int j = 0; j < 4; ++j){
      int orow = rbase + (lane >> 4)*4 + j;
      U[(size_t)orow*512 + col] = rne_bf16(acc[nt][j] + bc);
    }
  }
}

// ---------------- chain: 8 groups x 8 WGs (64-col slice), W_L+W_R in LDS -----
// c_k = tanh(U[b][k] + W_L*c_left [+ W_R*c_right]); per-WG padded store-flags.
__global__ __launch_bounds__(64) void k_chain3(
    const unsigned short* __restrict__ Wo, const unsigned short* __restrict__ U,
    const short* __restrict__ cL, const short* __restrict__ cR,
    const int* __restrict__ nred, const int* __restrict__ gIter,
    const int* __restrict__ anyLR, const unsigned short* __restrict__ zeroPg,
    unsigned short* __restrict__ CompBf, int* __restrict__ flags){
  __shared__ unsigned short Bsh[65536];           // 128 KiB: 4 ntiles x K=1024
  const int lane = threadIdx.x;
  const int g = blockIdx.x >> 3, wgN = blockIdx.x & 7;
  {
    const ushort8* src = reinterpret_cast<const ushort8*>(Wo) + (size_t)wgN*8192;
    ushort8* dst = reinterpret_cast<ushort8*>(Bsh);
    for (int x = lane; x < 8192; x += 64) dst[x] = src[x];
  }
  __syncthreads();

  const int colLane = lane & 15;
  const int aoff = (lane >> 4) * 16;              // bytes within 64B k-segment
  const int myb = rowB(g*16 + (lane & 15));
  const int myNred = nred[myb];
  const int iters = gIter[g];
  int bS[4], nredS[4];
  #pragma unroll
  for (int j = 0; j < 4; ++j){
    bS[j] = rowB(g*16 + (lane >> 4)*4 + j);
    nredS[j] = nred[bS[j]];
  }
  size_t Ubase[4];
  #pragma unroll
  for (int j = 0; j < 4; ++j)
    Ubase[j] = ((size_t)bS[j]*128)*512 + wgN*64 + colLane;

  for (int k = 0; k < iters; ++k){
    int afl = anyLR[g*128 + k];
    if (k > 0 && afl != 0){
      int guard = 0;
      for (;;){
        int fv = (lane < 8)
          ? __hip_atomic_load(flags + ((g*8 + lane) << 4), __ATOMIC_RELAXED, __HIP_MEMORY_SCOPE_AGENT)
          : 0x7FFFFFFF;
        if (__all(fv >= k)) break;
        __builtin_amdgcn_s_sleep(1);
        if (++guard > (1 << 26)) break;           // safety: never hang
      }
      __builtin_amdgcn_fence(__ATOMIC_ACQUIRE, "agent");
    }
    bool valid = (k < myNred);
    float4v acc[4];
    #pragma unroll
    for (int nt = 0; nt < 4; ++nt){
      #pragma unroll
      for (int j = 0; j < 4; ++j)
        acc[nt][j] = bf2f(U[Ubase[j] + (size_t)k*512 + nt*16]);
    }
    if (afl & 1){                                 // dynamic left (the chain dep)
      int rl = valid ? (int)cL[myb*128 + k] : -1;
      const char* pL = (rl >= 0)
        ? (const char*)(CompBf + ((size_t)myb*128 + rl)*512)
        : (const char*)zeroPg;
      short8 aL[16];
      #pragma unroll
      for (int kt = 0; kt < 16; ++kt)
        aL[kt] = *reinterpret_cast<const short8*>(pL + kt*64 + aoff);
      #pragma unroll
      for (int kt = 0; kt < 16; ++kt){
        #pragma unroll
        for (int nt = 0; nt < 4; ++nt)
          acc[nt] = __builtin_amdgcn_mfma_f32_16x16x32_bf16(
            aL[kt],
            *reinterpret_cast<const short8*>((const char*)Bsh + (((nt*32 + kt)*64 + lane) << 4)),
            acc[nt], 0, 0, 0);
      }
    }
    if (afl & 2){                                 // dynamic right (rare/general)
      int rr = valid ? (int)cR[myb*128 + k] : -1;
      const char* pR = (rr >= 0)
        ? (const char*)(CompBf + ((size_t)myb*128 + rr)*512)
        : (const char*)zeroPg;
      short8 aR[16];
      #pragma unroll
      for (int kt = 0; kt < 16; ++kt)
        aR[kt] = *reinterpret_cast<const short8*>(pR + kt*64 + aoff);
      #pragma unroll
      for (int kt = 0; kt < 16; ++kt){
        #pragma unroll
        for (int nt = 0; nt < 4; ++nt)
          acc[nt] = __builtin_amdgcn_mfma_f32_16x16x32_bf16(
            aR[kt],
            *reinterpret_cast<const short8*>((const char*)Bsh + (((nt*32 + 16 + kt)*64 + lane) << 4)),
            acc[nt], 0, 0, 0);
      }
    }
    #pragma unroll
    for (int nt = 0; nt < 4; ++nt){
      #pragma unroll
      for (int j = 0; j < 4; ++j){
        if (k < nredS[j]){
          float v = fast_tanh(acc[nt][j]);
          CompBf[((size_t)bS[j]*128 + k)*512 + wgN*64 + nt*16 + colLane] = rne_bf16(v);
        }
      }
    }
    __builtin_amdgcn_fence(__ATOMIC_RELEASE, "agent");
    if (lane == 0)
      __hip_atomic_store(flags + ((g*8 + wgN) << 4), k + 1,
                         __ATOMIC_RELAXED, __HIP_MEMORY_SCOPE_AGENT);
  }
}

// ---------------- output writer: pure copy/scatter, memory-bound ------------
__global__ __launch_bounds__(256) void k_out(
    const float* __restrict__ bufs, const unsigned short* __restrict__ CompBf,
    const short* __restrict__ redL, const short* __restrict__ redR,
    const int* __restrict__ encRef, float* __restrict__ out)
{
  int r = blockIdx.x*2 + (threadIdx.x >> 7);      // 65536 output rows of 512 f32
  int q = threadIdx.x & 127;                      // float4 index within row
  int ref, b;
  float* dst;
  if (r < B_){                                    // enc block
    b = r; ref = encRef[r];
    dst = out + (size_t)r*D_;
  } else {                                        // attended block
    int z = r - B_;
    b = z / 511; int s = z - b*511;
    dst = out + (size_t)B_*D_ + (size_t)z*D_;
    if (s == 510) ref = encRef[b];
    else { int t = s >> 1; ref = (s & 1) ? (int)redR[b*STEPS_ + t] : (int)redL[b*STEPS_ + t]; }
  }
  float4v v = {0.f, 0.f, 0.f, 0.f};
  if (ref >= 0 && ref < REF_COMP){
    v = reinterpret_cast<const float4v*>(bufs + ((size_t)b*T_ + ref)*D_)[q];
  } else if (ref >= REF_COMP && ref < REF_ZERO){
    ushort4v u = reinterpret_cast<const ushort4v*>(CompBf + ((size_t)b*128 + (ref - REF_COMP))*D_)[q];
    v[0] = bf2f(u[0]); v[1] = bf2f(u[1]); v[2] = bf2f(u[2]); v[3] = bf2f(u[3]);
  }
  reinterpret_cast<float4v*>(dst)[q] = v;
}

// ---------------- launch ----------------------------------------------------
extern "C" void kernel_launch(void* const* d_in, const int* in_sizes, int n_in,
                              void* d_out, int out_size, void* d_ws, size_t ws_size,
                              hipStream_t stream){
  const float* bufs = (const float*)d_in[0];
  const float* W    = (const float*)d_in[1];
  const float* bias = (const float*)d_in[2];
  const int*   tr   = (const int*)d_in[3];
  float* out = (float*)d_out;
  char* ws = (char*)d_ws;

  unsigned short* Wo     = (unsigned short*)(ws);               //  1,048,576
  unsigned short* CompBf = (unsigned short*)(ws + 1048576);     // 16,777,216
  unsigned short* U      = (unsigned short*)(ws + 17825792);    // 16,777,216
  short* redL   = (short*)(ws + 34603008);                      //     65,536
  short* redR   = (short*)(ws + 34668544);                      //     65,536
  short* uL     = (short*)(ws + 34734080);                      //     32,768
  short* uR     = (short*)(ws + 34766848);                      //     32,768
  short* cL     = (short*)(ws + 34799616);                      //     32,768
  short* cR     = (short*)(ws + 34832384);                      //     32,768
  int* nred     = (int*)(ws + 34865152);                        //        512
  int* encRef   = (int*)(ws + 34865664);                        //        512
  int* gIter    = (int*)(ws + 34866176);                        //        256
  int* flags    = (int*)(ws + 34866432);                        //      4,096
  int* anyLR    = (int*)(ws + 34870528);                        //      4,096
  unsigned short* zeroPg = (unsigned short*)(ws + 34874624);    //      2,048

  k_zero<<<1, 256, 0, stream>>>(flags, anyLR, gIter, zeroPg);
  k_prepass2<<<128, 64, 0, stream>>>(tr, redL, redR, uL, uR, cL, cR, nred, encRef, gIter, anyLR);
  k_wprep<<<2048, 256, 0, stream>>>(W, Wo);
  k_ugemm<<<1024, 256, 0, stream>>>(bufs, bias, Wo, uL, uR, (const float*)zeroPg, U);
  k_chain3<<<64, 64, 0, stream>>>(Wo, U, cL, cR, nred, gIter, anyLR, zeroPg, CompBf, flags);
  k_out<<<32768, 256, 0, stream>>>(bufs, CompBf, redL, redR, encRef, out);
}